// Round 5
// baseline (386.864 us; speedup 1.0000x reference)
//
#include <hip/hip_runtime.h>
#include <hip/hip_bf16.h>

// Problem constants (AriaExperts): tokens=2048, hidden=1024, inter=2048, E=8, topk=2
constexpr int T = 2048;
constexpr int H = 1024;
constexpr int I = 2048;
constexpr int N2 = 2 * I;      // fc1 weight cols (proj|gate)
constexpr int RCAP = 5120;     // padded row capacity
constexpr int MAXT = 40;       // max 128-row tiles

// ws int-offset map (ints)
constexpr int WS_OFF = 16;                 // [16,25) expert row offsets (padded)
constexpr int WS_TEXP = 32;                // [32,72) tile -> expert
constexpr int WS_TOPKP = 4256;             // [4256,8352) token scales (float)
constexpr int WS_ROWTOK = 8352;            // [8352,13472) row -> token
constexpr int WS_TOKROW = 13472;           // [13472,17568) token -> 2 rows
// ws byte offsets
constexpr size_t WSB_ZROW = 114688;        // bf16 zero row, H elements
constexpr size_t WSB_HSB  = 131072;        // bf16 hidden_states [T][H] (4 MB)
constexpr size_t WSB_ACT  = 8u << 20;      // bf16 act [RCAP][I] (20 MB)
constexpr size_t WSB_PW1  = 32u << 20;     // packed bf16 w1 (64 MB); reused as eo[2][RCAP][H] fp32 (40 MB)
constexpr size_t WSB_PW2  = 96u << 20;     // packed bf16 w2 (32 MB) -> 128 MB ws

constexpr int PW1_BLKS = 2048;             // (e:8, kd:128, ch:2)
constexpr int PW2_BLKS = 2048;             // (e:8, kd:256)
constexpr int HSB_BLKS = T * H / 2048;     // 1024
constexpr int FC1_BLKS = 32 * MAXT;        // 1280

typedef __attribute__((ext_vector_type(4))) float f32x4;
typedef __attribute__((ext_vector_type(8))) short s16x8;
typedef __attribute__((ext_vector_type(4))) short s16x4;

__device__ __forceinline__ short f2bf(float f) {
    unsigned u = __float_as_uint(f);
    u += 0x7FFFu + ((u >> 16) & 1u);   // round-to-nearest-even
    return (short)(u >> 16);
}

#define MFMA16(a, b, c) __builtin_amdgcn_mfma_f32_16x16x32_bf16(a, b, c, 0, 0, 0)

__device__ __forceinline__ void gl2lds16(const void* g, void* l) {
    __builtin_amdgcn_global_load_lds(
        (const __attribute__((address_space(1))) void*)g,
        (__attribute__((address_space(3))) void*)l, 16, 0, 0);
}

// ---------------- routing: top2+softmax, scan-based slots, no atomics (1 block) ----------------
__global__ __launch_bounds__(256) void routing_kernel(const float* __restrict__ logits,
                                                      int* __restrict__ wsi,
                                                      float* __restrict__ wsf) {
    __shared__ unsigned char lds_e[T * 2];     // expert id per assignment
    __shared__ int pre[8][257];                // per-expert exclusive prefix over threads
    __shared__ int base[9];
    const int t = threadIdx.x;

    for (int r = t; r < RCAP; r += 256) wsi[WS_ROWTOK + r] = -1;
    unsigned short* zr = (unsigned short*)((char*)wsi + WSB_ZROW);
    for (int i = t; i < H; i += 256) zr[i] = 0;

    unsigned long long cnt = 0;                // 8 bytes = 8 counters (max 16 each)
    #pragma unroll
    for (int j = 0; j < 8; j++) {
        int tok = t * 8 + j;
        const float* l = logits + tok * 8;
        float v0 = -1e30f; int i0 = 0;
        #pragma unroll
        for (int i = 0; i < 8; i++) { float v = l[i]; if (v > v0) { v0 = v; i0 = i; } }
        float v1 = -1e30f; int i1 = 0;
        #pragma unroll
        for (int i = 0; i < 8; i++) { if (i == i0) continue; float v = l[i]; if (v > v1) { v1 = v; i1 = i; } }
        float ex = __expf(v1 - v0);
        float inv = 1.f / (1.f + ex);
        wsf[WS_TOPKP + tok * 2] = inv;
        wsf[WS_TOPKP + tok * 2 + 1] = ex * inv;
        lds_e[tok * 2] = (unsigned char)i0;
        lds_e[tok * 2 + 1] = (unsigned char)i1;
        cnt += 1ull << (i0 * 8);
        cnt += 1ull << (i1 * 8);
    }
    #pragma unroll
    for (int e = 0; e < 8; e++) pre[e][t + 1] = (int)((cnt >> (e * 8)) & 0xff);
    __syncthreads();
    if (t < 8) {                               // serial per-expert scan (256 adds)
        int s = 0; pre[t][0] = 0;
        for (int i = 1; i <= 256; i++) { s += pre[t][i]; pre[t][i] = s; }
    }
    __syncthreads();
    if (t == 0) {
        int acc = 0;
        for (int e = 0; e < 8; e++) { base[e] = acc; acc += (pre[e][256] + 127) & ~127; }
        base[8] = acc;
        for (int e = 0; e < 9; e++) wsi[WS_OFF + e] = base[e];
    }
    __syncthreads();
    for (int tt = t; tt < MAXT; tt += 256) {
        int rb = tt * 128, ex = 0;
        for (int e = 0; e < 8; e++)
            if (rb >= base[e] && rb < base[e + 1]) ex = e;
        wsi[WS_TEXP + tt] = ex;
    }
    unsigned long long run = 0;
    #pragma unroll
    for (int j = 0; j < 8; j++) {
        int tok = t * 8 + j;
        #pragma unroll
        for (int k = 0; k < 2; k++) {
            int e = lds_e[tok * 2 + k];
            int r = base[e] + pre[e][t] + (int)((run >> (e * 8)) & 0xff);
            run += 1ull << (e * 8);
            wsi[WS_ROWTOK + r] = tok;
            wsi[WS_TOKROW + tok * 2 + k] = r;
        }
    }
}

// ---------------- prep: sequential-read transpose-pack (w1, w2) + hs->bf16 ----------------
// pw1: [e][ct:32][k0i:32] x 4096 = [kg:4][n:128][kk:8]
//   tile col n: sub=n>>5 -> global col = (sub&1)*I + ct*64 + (sub>>1)*32 + (n&31)
// pw2: [e][ht:8][k0i:64] x 4096 = [kg:4][n:128][kk:8]; global col = ht*128+n
__global__ __launch_bounds__(256) void prep_kernel(
    const float* __restrict__ w1, unsigned short* __restrict__ pw1,
    const float* __restrict__ w2, unsigned short* __restrict__ pw2,
    const float* __restrict__ hs, unsigned short* __restrict__ hsb) {
    __shared__ __align__(16) short L[8 * 2048];   // [kk:8][c] (w1: c<2048, w2: c<1024)
    const int t = threadIdx.x;

    if (blockIdx.x < PW1_BLKS) {
        // block = (e, kd:128, ch:2): rows kd*8..+8, cols ch*2048..+2048 of w1[e]
        int b = blockIdx.x;
        int ch = b & 1, kd = (b >> 1) & 127, e = b >> 8;
        const float* s0 = w1 + (size_t)e * H * N2 + (size_t)(kd * 8) * N2 + ch * I;
        #pragma unroll
        for (int j = 0; j < 16; j++) {
            int cc = j * 256 + t;              // 4096 f32x4 chunks
            int r = cc >> 9, cx = cc & 511;
            f32x4 v = *(const f32x4*)(s0 + (size_t)r * N2 + cx * 4);
            s16x4 s = {f2bf(v[0]), f2bf(v[1]), f2bf(v[2]), f2bf(v[3])};
            *(s16x4*)&L[r * 2048 + cx * 4] = s;
        }
        __syncthreads();
        const int k0i = kd >> 2, kg = kd & 3;
        #pragma unroll
        for (int j = 0; j < 8; j++) {
            int u = j * 256 + t;               // 2048 output units (ct:32 x nh:64)
            int ct = u >> 6, nh = u & 63;
            int sh = nh >> 5, within = nh & 31;
            int n = (sh * 2 + ch) * 32 + within;
            int cl = ct * 64 + sh * 32 + within;
            s16x8 o;
            #pragma unroll
            for (int kk = 0; kk < 8; kk++) o[kk] = L[kk * 2048 + cl];
            *(s16x8*)(pw1 + (size_t)((e * 32 + ct) * 32 + k0i) * 4096 + kg * 1024 + n * 8) = o;
        }
    } else if (blockIdx.x < PW1_BLKS + PW2_BLKS) {
        // block = (e, kd:256): rows kd*8..+8 (full H cols) of w2[e] — contiguous 32 KB read
        int b = blockIdx.x - PW1_BLKS;
        int kd = b & 255, e = b >> 8;
        const float* s0 = w2 + (size_t)e * I * H + (size_t)(kd * 8) * H;
        #pragma unroll
        for (int j = 0; j < 8; j++) {
            int cc = j * 256 + t;              // 2048 f32x4 chunks, fully contiguous
            f32x4 v = *(const f32x4*)(s0 + cc * 4);
            int r = cc >> 8, cx = cc & 255;
            s16x4 s = {f2bf(v[0]), f2bf(v[1]), f2bf(v[2]), f2bf(v[3])};
            *(s16x4*)&L[r * 1024 + cx * 4] = s;
        }
        __syncthreads();
        const int k0i = kd >> 2, kg = kd & 3;
        #pragma unroll
        for (int j = 0; j < 4; j++) {
            int u = j * 256 + t;               // 1024 units (ht:8 x n:128); c_local = u
            int ht = u >> 7, n = u & 127;
            s16x8 o;
            #pragma unroll
            for (int kk = 0; kk < 8; kk++) o[kk] = L[kk * 1024 + u];
            *(s16x8*)(pw2 + (size_t)((e * 8 + ht) * 64 + k0i) * 4096 + kg * 1024 + n * 8) = o;
        }
    } else {
        int i = ((blockIdx.x - PW1_BLKS - PW2_BLKS) * 256 + t) * 8;
        f32x4 a = *(const f32x4*)(hs + i);
        f32x4 b = *(const f32x4*)(hs + i + 4);
        s16x8 s = {f2bf(a[0]), f2bf(a[1]), f2bf(a[2]), f2bf(a[3]),
                   f2bf(b[0]), f2bf(b[1]), f2bf(b[2]), f2bf(b[3])};
        *(s16x8*)(hsb + i) = s;
    }
}

// ---------------- fc1 (128x128, BK=32) + SwiGLU ----------------
__global__ __launch_bounds__(256, 4) void fc1_kernel(
    const unsigned short* __restrict__ hsb, const unsigned short* __restrict__ pw1,
    const int* __restrict__ wsi, const unsigned short* __restrict__ zrow,
    unsigned short* __restrict__ act) {
    __shared__ __align__(16) unsigned short Al[512 * 8];    // [kg:4][m:128][8]
    __shared__ __align__(16) unsigned short Bl[512 * 8];    // [kg:4][n:128][8]
    const int t = threadIdx.x;
    const int ct = blockIdx.x & 31, rt = blockIdx.x >> 5;
    const int rowb = rt * 128;
    if (rowb >= wsi[WS_OFF + 8]) return;
    const int e = wsi[WS_TEXP + rt];
    const unsigned short* pb = pw1 + (size_t)((e * 32 + ct) * 32) * 4096;

    const int m = t & 127;
    const int tok = wsi[WS_ROWTOK + rowb + m];
    const unsigned short* rp = (tok >= 0) ? (hsb + (size_t)tok * H) : zrow;
    const int kga = t >> 7;

    const int lane = t & 63, w = t >> 6, wr = w >> 1, wc = w & 1;
    const int q = lane >> 4, l16 = lane & 15;

    f32x4 zero = {0.f, 0.f, 0.f, 0.f};
    f32x4 acc[4][4];
    #pragma unroll
    for (int mi = 0; mi < 4; mi++)
        #pragma unroll
        for (int ni = 0; ni < 4; ni++) acc[mi][ni] = zero;

    for (int k0i = 0; k0i < 32; k0i++) {
        const int k0 = k0i * 32;
        gl2lds16(rp + k0 + kga * 8, &Al[t * 8]);
        gl2lds16(rp + k0 + (kga + 2) * 8, &Al[(t + 256) * 8]);
        const unsigned short* ps = pb + (size_t)k0i * 4096;
        gl2lds16(ps + t * 8, &Bl[t * 8]);
        gl2lds16(ps + (t + 256) * 8, &Bl[(t + 256) * 8]);
        __syncthreads();

        s16x8 af[4], bf[4];
        #pragma unroll
        for (int mi = 0; mi < 4; mi++)
            af[mi] = *(const s16x8*)&Al[(q * 128 + wr * 64 + mi * 16 + l16) * 8];
        #pragma unroll
        for (int ni = 0; ni < 4; ni++)
            bf[ni] = *(const s16x8*)&Bl[(q * 128 + wc * 64 + ni * 16 + l16) * 8];
        #pragma unroll
        for (int mi = 0; mi < 4; mi++)
            #pragma unroll
            for (int ni = 0; ni < 4; ni++)
                acc[mi][ni] = MFMA16(af[mi], bf[ni], acc[mi][ni]);
        __syncthreads();
    }

    // epilogue: wave cols = 32 proj + 32 gate (ni 0,1 = proj; ni 2,3 = matching gate)
    #pragma unroll
    for (int mi = 0; mi < 4; mi++)
        #pragma unroll
        for (int r = 0; r < 4; r++) {
            int row = rowb + wr * 64 + mi * 16 + q * 4 + r;
            #pragma unroll
            for (int ni = 0; ni < 2; ni++) {
                int col = ct * 64 + wc * 32 + ni * 16 + l16;
                float p = acc[mi][ni][r], g = acc[mi][ni + 2][r];
                float val = p * g / (1.f + __expf(-p));
                act[(size_t)row * I + col] = (unsigned short)f2bf(val);
            }
        }
}

// ---------------- fc2 (128x128, BK=32, K-split x2) -> eo partials, no atomics ----------------
__global__ __launch_bounds__(256, 4) void fc2_kernel(
    const unsigned short* __restrict__ act, const unsigned short* __restrict__ pw2,
    const int* __restrict__ wsi, float* __restrict__ eo) {
    __shared__ __align__(16) unsigned short Al[512 * 8];
    __shared__ __align__(16) unsigned short Bl[512 * 8];
    const int t = threadIdx.x;
    const int ht = blockIdx.x, rt = blockIdx.y, ks = blockIdx.z;
    const int rowb = rt * 128;
    if (rowb >= wsi[WS_OFF + 8]) return;
    const int e = wsi[WS_TEXP + rt];
    const unsigned short* pb = pw2 + (size_t)((e * 8 + ht) * 64) * 4096;

    const int m = t & 127;
    const unsigned short* rp = act + (size_t)(rowb + m) * I;
    const int kga = t >> 7;

    const int lane = t & 63, w = t >> 6, wr = w >> 1, wc = w & 1;
    const int q = lane >> 4, l16 = lane & 15;

    f32x4 zero = {0.f, 0.f, 0.f, 0.f};
    f32x4 acc[4][4];
    #pragma unroll
    for (int mi = 0; mi < 4; mi++)
        #pragma unroll
        for (int ni = 0; ni < 4; ni++) acc[mi][ni] = zero;

    for (int k0i = ks * 32; k0i < ks * 32 + 32; k0i++) {
        const int k0 = k0i * 32;
        gl2lds16(rp + k0 + kga * 8, &Al[t * 8]);
        gl2lds16(rp + k0 + (kga + 2) * 8, &Al[(t + 256) * 8]);
        const unsigned short* ps = pb + (size_t)k0i * 4096;
        gl2lds16(ps + t * 8, &Bl[t * 8]);
        gl2lds16(ps + (t + 256) * 8, &Bl[(t + 256) * 8]);
        __syncthreads();

        s16x8 af[4], bf[4];
        #pragma unroll
        for (int mi = 0; mi < 4; mi++)
            af[mi] = *(const s16x8*)&Al[(q * 128 + wr * 64 + mi * 16 + l16) * 8];
        #pragma unroll
        for (int ni = 0; ni < 4; ni++)
            bf[ni] = *(const s16x8*)&Bl[(q * 128 + wc * 64 + ni * 16 + l16) * 8];
        #pragma unroll
        for (int mi = 0; mi < 4; mi++)
            #pragma unroll
            for (int ni = 0; ni < 4; ni++)
                acc[mi][ni] = MFMA16(af[mi], bf[ni], acc[mi][ni]);
        __syncthreads();
    }

    float* ed = eo + (size_t)ks * RCAP * H;
    #pragma unroll
    for (int mi = 0; mi < 4; mi++)
        #pragma unroll
        for (int r = 0; r < 4; r++) {
            int row = rowb + wr * 64 + mi * 16 + q * 4 + r;
            #pragma unroll
            for (int ni = 0; ni < 4; ni++) {
                int col = ht * 128 + wc * 64 + ni * 16 + l16;
                ed[(size_t)row * H + col] = acc[mi][ni][r];
            }
        }
}

// ---------------- combine: out[tok] = s0*(eo0[r0]+eo1[r0]) + s1*(eo0[r1]+eo1[r1]) ----------------
__global__ __launch_bounds__(256) void combine_kernel(
    const float* __restrict__ eo, const int* __restrict__ wsi,
    const float* __restrict__ wsf, float* __restrict__ out) {
    const int tok = blockIdx.x;
    const int r0 = wsi[WS_TOKROW + tok * 2], r1 = wsi[WS_TOKROW + tok * 2 + 1];
    const float s0 = wsf[WS_TOPKP + tok * 2], s1 = wsf[WS_TOPKP + tok * 2 + 1];
    const float* a0 = eo + (size_t)r0 * H;
    const float* a1 = eo + (size_t)RCAP * H + (size_t)r0 * H;
    const float* b0 = eo + (size_t)r1 * H;
    const float* b1 = eo + (size_t)RCAP * H + (size_t)r1 * H;
    const int c = threadIdx.x * 4;
    f32x4 va0 = *(const f32x4*)(a0 + c), va1 = *(const f32x4*)(a1 + c);
    f32x4 vb0 = *(const f32x4*)(b0 + c), vb1 = *(const f32x4*)(b1 + c);
    f32x4 r;
    #pragma unroll
    for (int i = 0; i < 4; i++) r[i] = s0 * (va0[i] + va1[i]) + s1 * (vb0[i] + vb1[i]);
    *(f32x4*)(out + (size_t)tok * H + c) = r;
}

extern "C" void kernel_launch(void* const* d_in, const int* in_sizes, int n_in,
                              void* d_out, int out_size, void* d_ws, size_t ws_size,
                              hipStream_t stream) {
    const float* hs     = (const float*)d_in[0];
    const float* logits = (const float*)d_in[1];
    const float* w1     = (const float*)d_in[2];
    const float* w2     = (const float*)d_in[3];
    float* out = (float*)d_out;
    int* wsi = (int*)d_ws;
    float* wsf = (float*)d_ws;
    unsigned short* zrow = (unsigned short*)((char*)d_ws + WSB_ZROW);
    unsigned short* hsb  = (unsigned short*)((char*)d_ws + WSB_HSB);
    unsigned short* act  = (unsigned short*)((char*)d_ws + WSB_ACT);
    unsigned short* pw1  = (unsigned short*)((char*)d_ws + WSB_PW1);
    unsigned short* pw2  = (unsigned short*)((char*)d_ws + WSB_PW2);
    float* eo = (float*)((char*)d_ws + WSB_PW1);   // aliases pw1 (consumed by fc1 before fc2 runs)

    routing_kernel<<<1, 256, 0, stream>>>(logits, wsi, wsf);
    prep_kernel<<<PW1_BLKS + PW2_BLKS + HSB_BLKS, 256, 0, stream>>>(w1, pw1, w2, pw2, hs, hsb);
    fc1_kernel<<<FC1_BLKS, 256, 0, stream>>>(hsb, pw1, wsi, zrow, act);
    fc2_kernel<<<dim3(8, MAXT, 2), 256, 0, stream>>>(act, pw2, wsi, eo);
    combine_kernel<<<T, 256, 0, stream>>>(eo, wsi, wsf, out);
}